// Round 1
// baseline (481.482 us; speedup 1.0000x reference)
//
#include <hip/hip_runtime.h>

// MultiheadSelfAttention: x(2,2048,1024) f32 -> QKV proj + RoPE -> causal attn -> out proj
// Round 0: correctness-first MFMA pipeline, bf16 internal, fp32 I/O.

#define BATCH 2
#define SEQ   2048
#define NH    16
#define HD    64
#define DM    1024
#define MTOT  (BATCH*SEQ)   // 4096

typedef __attribute__((ext_vector_type(8))) short bf16x8;
typedef __attribute__((ext_vector_type(4))) float f32x4;
typedef unsigned short u16;
typedef unsigned int   u32;

__device__ __forceinline__ float b2f(u16 h){ return __uint_as_float(((u32)h) << 16); }
__device__ __forceinline__ u16 f2b(float f){
  u32 u = __float_as_uint(f);
  u32 r = (u + 0x7FFFu + ((u >> 16) & 1u)) >> 16;   // RNE
  return (u16)r;
}
__device__ __forceinline__ f32x4 mfma16(bf16x8 a, bf16x8 b, f32x4 c){
  return __builtin_amdgcn_mfma_f32_16x16x32_bf16(a, b, c, 0, 0, 0);
}

// ---------------- fp32 -> bf16 conversion for x and the 4 weights ----------------
__global__ __launch_bounds__(256) void cvt_all(const float* __restrict__ x,
    const float* __restrict__ wq, const float* __restrict__ wk,
    const float* __restrict__ wv, const float* __restrict__ wo,
    u16* __restrict__ xb, u16* __restrict__ wb)
{
  const long NX = (long)MTOT * DM;       // 4194304
  const long NW = (long)DM * DM;         // 1048576
  const long tot4 = (NX + 4*NW) >> 2;
  for (long t = (long)blockIdx.x*blockDim.x + threadIdx.x; t < tot4;
       t += (long)gridDim.x*blockDim.x){
    long e = t << 2;
    const float* s; u16* d;
    if (e < NX){ s = x + e; d = xb + e; }
    else {
      long j = e - NX; int z = (int)(j >> 20);
      const float* ws = (z==0)?wq:(z==1)?wk:(z==2)?wv:wo;
      s = ws + (j & (NW-1)); d = wb + j;
    }
    float4 v = *(const float4*)s;
    u32 lo = (u32)f2b(v.x) | ((u32)f2b(v.y) << 16);
    u32 hi = (u32)f2b(v.z) | ((u32)f2b(v.w) << 16);
    uint2 o; o.x = lo; o.y = hi;
    *(uint2*)d = o;
  }
}

// ---------------- RoPE cos/sin table: [SEQ][32] float2 ----------------
__global__ __launch_bounds__(256) void rope_table(float2* __restrict__ tab){
  int t = blockIdx.x*blockDim.x + threadIdx.x;
  if (t >= SEQ*32) return;
  int s = t >> 5, i = t & 31;
  float inv = 1.0f / powf(10000.0f, (float)i * (1.0f/32.0f));
  float a = (float)s * inv;
  tab[t] = make_float2(cosf(a), sinf(a));
}

// ---------------- GEMM core: C[m][n] = sum_k A[m][k]*B[n][k]  (64x64 tile, 4 waves) ----
// A-frag: lane row=l%16, k=8*(l/16)+j (contiguous). B-frag: lane col=l%16, same k chunk.
// D: col=lane&15, row=(lane>>4)*4+reg  [verified layout, learn_hip m89/m91]
__device__ __forceinline__ void gemm_core(const u16* __restrict__ A, const u16* __restrict__ Bm,
                                          int mbase, int nbase, int wr, int wc, int g, int c,
                                          f32x4 acc[2][2])
{
  const u16* Ap = A  + (long)(mbase + wr + c)*DM + g*8;
  const u16* Bp = Bm + (long)(nbase + wc + c)*DM + g*8;
  #pragma unroll 2
  for (int k0 = 0; k0 < DM; k0 += 32){
    bf16x8 a0 = *(const bf16x8*)(Ap + k0);
    bf16x8 a1 = *(const bf16x8*)(Ap + 16L*DM + k0);
    bf16x8 b0 = *(const bf16x8*)(Bp + k0);
    bf16x8 b1 = *(const bf16x8*)(Bp + 16L*DM + k0);
    acc[0][0] = mfma16(a0, b0, acc[0][0]);
    acc[0][1] = mfma16(a0, b1, acc[0][1]);
    acc[1][0] = mfma16(a1, b0, acc[1][0]);
    acc[1][1] = mfma16(a1, b1, acc[1][1]);
  }
}

// QKV projection: grid (N/64=16, M/64=64, 3), 256 threads. bf16 out to qkvraw.
__global__ __launch_bounds__(256) void gemm_qkv(const u16* __restrict__ xb,
                                                const u16* __restrict__ wb,
                                                u16* __restrict__ qkvr)
{
  int z = blockIdx.z;
  const u16* Bm = wb + (long)z * DM * DM;
  u16* C = qkvr + (long)z * MTOT * DM;
  int nbase = blockIdx.x*64, mbase = blockIdx.y*64;
  int w = threadIdx.x >> 6, l = threadIdx.x & 63, g = l >> 4, c = l & 15;
  int wr = (w >> 1)*32, wc = (w & 1)*32;
  f32x4 acc[2][2] = {};
  gemm_core(xb, Bm, mbase, nbase, wr, wc, g, c, acc);
  #pragma unroll
  for (int i = 0; i < 2; i++)
    #pragma unroll
    for (int j = 0; j < 2; j++)
      #pragma unroll
      for (int r = 0; r < 4; r++){
        int row = mbase + wr + i*16 + 4*g + r;
        int col = nbase + wc + j*16 + c;
        C[(long)row*DM + col] = f2b(acc[i][j][r]);
      }
}

// Output projection: fp32 out to d_out.
__global__ __launch_bounds__(256) void gemm_out(const u16* __restrict__ Zb,
                                                const u16* __restrict__ wob,
                                                float* __restrict__ out)
{
  int nbase = blockIdx.x*64, mbase = blockIdx.y*64;
  int w = threadIdx.x >> 6, l = threadIdx.x & 63, g = l >> 4, c = l & 15;
  int wr = (w >> 1)*32, wc = (w & 1)*32;
  f32x4 acc[2][2] = {};
  gemm_core(Zb, wob, mbase, nbase, wr, wc, g, c, acc);
  #pragma unroll
  for (int i = 0; i < 2; i++)
    #pragma unroll
    for (int j = 0; j < 2; j++)
      #pragma unroll
      for (int r = 0; r < 4; r++){
        int row = mbase + wr + i*16 + 4*g + r;
        int col = nbase + wc + j*16 + c;
        out[(long)row*DM + col] = acc[i][j][r];
      }
}

// ---------------- RoPE apply + scatter to attention layouts ----------------
// Q,K: [b,h,s,d] bf16 (rope'd, interleaved pairs).  V: transposed to [b,h,d,s].
__global__ __launch_bounds__(256) void rope_scatter(const u16* __restrict__ qkvr,
    u16* __restrict__ Qd, u16* __restrict__ Kd, u16* __restrict__ Vt,
    const float2* __restrict__ tab, const int* __restrict__ pos)
{
  int st = blockIdx.x, h = blockIdx.y, b = blockIdx.z;
  int s0 = st*64;
  const u16* Qraw = qkvr;
  const u16* Kraw = qkvr + (long)MTOT*DM;
  const u16* Vraw = qkvr + 2L*MTOT*DM;

  for (int t = threadIdx.x; t < 64*32; t += 256){
    int sl = t >> 5, i = t & 31;
    int s = s0 + sl;
    int p = pos[b*SEQ + s];
    if (p < 0) p = 0; if (p >= SEQ) p = SEQ - 1;
    float2 cs = tab[p*32 + i];
    long inoff  = (long)(b*SEQ + s)*DM + h*HD + 2*i;
    long outoff = ((long)(b*NH + h)*SEQ + s)*HD + 2*i;
    u32 qe = *(const u32*)(Qraw + inoff);
    float x1 = b2f((u16)(qe & 0xffff)), x2 = b2f((u16)(qe >> 16));
    float r1 = x1*cs.x - x2*cs.y;
    float r2 = x1*cs.y + x2*cs.x;
    *(u32*)(Qd + outoff) = (u32)f2b(r1) | ((u32)f2b(r2) << 16);
    u32 ke = *(const u32*)(Kraw + inoff);
    x1 = b2f((u16)(ke & 0xffff)); x2 = b2f((u16)(ke >> 16));
    r1 = x1*cs.x - x2*cs.y;
    r2 = x1*cs.y + x2*cs.x;
    *(u32*)(Kd + outoff) = (u32)f2b(r1) | ((u32)f2b(r2) << 16);
  }

  // V transpose 64x64 tile via padded LDS (both global sides coalesced 16B)
  __shared__ u16 vt[64][65];
  for (int t = threadIdx.x; t < 64*8; t += 256){
    int sl = t >> 3, ch = (t & 7)*8;
    bf16x8 v = *(const bf16x8*)(Vraw + (long)(b*SEQ + s0 + sl)*DM + h*HD + ch);
    #pragma unroll
    for (int j = 0; j < 8; j++) vt[sl][ch + j] = (u16)v[j];
  }
  __syncthreads();
  for (int t = threadIdx.x; t < 64*8; t += 256){
    int d = t >> 3, ch = (t & 7)*8;
    bf16x8 v;
    #pragma unroll
    for (int j = 0; j < 8; j++) v[j] = (short)vt[ch + j][d];
    *(bf16x8*)(Vt + ((long)(b*NH + h)*HD + d)*SEQ + s0 + ch) = v;
  }
}

// ---------------- causal flash attention: 1 wave per 16-query tile ----------------
__global__ __launch_bounds__(64) void attn(const u16* __restrict__ Q, const u16* __restrict__ K,
                                           const u16* __restrict__ Vt, u16* __restrict__ Z)
{
  int qt = blockIdx.x, h = blockIdx.y, b = blockIdx.z;
  int qbase = qt*16;
  int l = threadIdx.x, g = l >> 4, c = l & 15;
  const u16* Qp = Q  + ((long)(b*NH + h)*SEQ + qbase)*HD;
  const u16* Kp = K  + (long)(b*NH + h)*SEQ*HD;
  const u16* Vp = Vt + (long)(b*NH + h)*HD*SEQ;
  __shared__ u16 P_lds[16*32];

  // Q A-fragments: row=c, d-chunks (0-31) and (32-63), 8 contiguous d per lane
  bf16x8 qf0 = *(const bf16x8*)(Qp + c*HD + g*8);
  bf16x8 qf1 = *(const bf16x8*)(Qp + c*HD + 32 + g*8);

  f32x4 accz[4] = {};
  float m[4], lsum[4];
  #pragma unroll
  for (int r = 0; r < 4; r++){ m[r] = -1e30f; lsum[r] = 0.f; }

  int ntiles = (qbase + 16 + 31) >> 5;
  for (int t = 0; t < ntiles; ++t){
    int kbase = t*32;
    // scores: D[q][key], two 16-key sub-tiles, accumulate d=0..63 over 2 MFMAs each
    f32x4 s[2];
    #pragma unroll
    for (int sub = 0; sub < 2; sub++){
      const u16* kp = Kp + (long)(kbase + sub*16 + c)*HD + g*8;
      bf16x8 k0 = *(const bf16x8*)(kp);
      bf16x8 k1 = *(const bf16x8*)(kp + 32);
      f32x4 z4 = {};
      z4 = mfma16(qf0, k0, z4);
      z4 = mfma16(qf1, k1, z4);
      s[sub] = z4;
    }
    bool edge = (kbase + 31 > qbase);
    #pragma unroll
    for (int sub = 0; sub < 2; sub++)
      #pragma unroll
      for (int r = 0; r < 4; r++){
        float v = s[sub][r]*0.125f;
        if (edge && (kbase + sub*16 + c > qbase + 4*g + r)) v = -1e30f;
        s[sub][r] = v;
      }
    // online softmax (rows live on reg index r; reduce over the 16 col-lanes)
    float tmax[4], f[4], psum[4];
    #pragma unroll
    for (int r = 0; r < 4; r++) tmax[r] = fmaxf(s[0][r], s[1][r]);
    #pragma unroll
    for (int off = 1; off < 16; off <<= 1)
      #pragma unroll
      for (int r = 0; r < 4; r++) tmax[r] = fmaxf(tmax[r], __shfl_xor(tmax[r], off));
    #pragma unroll
    for (int r = 0; r < 4; r++){
      float nm = fmaxf(m[r], tmax[r]);
      f[r] = __expf(m[r] - nm);
      m[r] = nm;
    }
    #pragma unroll
    for (int sub = 0; sub < 2; sub++)
      #pragma unroll
      for (int r = 0; r < 4; r++) s[sub][r] = __expf(s[sub][r] - m[r]);
    #pragma unroll
    for (int r = 0; r < 4; r++) psum[r] = s[0][r] + s[1][r];
    #pragma unroll
    for (int off = 1; off < 16; off <<= 1)
      #pragma unroll
      for (int r = 0; r < 4; r++) psum[r] += __shfl_xor(psum[r], off);
    #pragma unroll
    for (int r = 0; r < 4; r++) lsum[r] = lsum[r]*f[r] + psum[r];
    #pragma unroll
    for (int dt = 0; dt < 4; dt++)
      #pragma unroll
      for (int r = 0; r < 4; r++) accz[dt][r] *= f[r];

    // P (D-layout) -> LDS -> A-fragment layout for PV
    #pragma unroll
    for (int sub = 0; sub < 2; sub++)
      #pragma unroll
      for (int r = 0; r < 4; r++)
        P_lds[(4*g + r)*32 + sub*16 + c] = f2b(s[sub][r]);
    __syncthreads();
    bf16x8 pf = *(const bf16x8*)(&P_lds[c*32 + g*8]);   // row=c, keys 8g..8g+7
    #pragma unroll
    for (int dt = 0; dt < 4; dt++){
      bf16x8 vf = *(const bf16x8*)(Vp + (long)(dt*16 + c)*SEQ + kbase + g*8);
      accz[dt] = mfma16(pf, vf, accz[dt]);
    }
    __syncthreads();
  }
  // epilogue: divide by row-sum, write Z[b, s, h*64+d] bf16
  #pragma unroll
  for (int dt = 0; dt < 4; dt++)
    #pragma unroll
    for (int r = 0; r < 4; r++){
      float zv = accz[dt][r] / lsum[r];
      int row = qbase + 4*g + r;
      int col = dt*16 + c;
      Z[(long)(b*SEQ + row)*DM + h*HD + col] = f2b(zv);
    }
}

extern "C" void kernel_launch(void* const* d_in, const int* in_sizes, int n_in,
                              void* d_out, int out_size, void* d_ws, size_t ws_size,
                              hipStream_t stream)
{
  const float* x  = (const float*)d_in[0];
  const int*   pos= (const int*)d_in[1];
  const float* wq = (const float*)d_in[2];
  const float* wk = (const float*)d_in[3];
  const float* wv = (const float*)d_in[4];
  const float* wo = (const float*)d_in[5];
  float* out = (float*)d_out;

  const long NX = (long)MTOT*DM;   // 4.19M elems
  const long NW = (long)DM*DM;
  char* p = (char*)d_ws;
  u16* xb   = (u16*)p;  p += NX*2;
  u16* wb   = (u16*)p;  p += 4*NW*2;
  u16* qkvr = (u16*)p;  p += 3*NX*2;
  u16* Qd   = (u16*)p;  p += NX*2;
  u16* Kd   = (u16*)p;  p += NX*2;
  u16* Vt   = (u16*)p;  p += NX*2;
  u16* Zb   = (u16*)p;  p += NX*2;
  float2* tab = (float2*)p; p += (long)SEQ*32*sizeof(float2);
  (void)ws_size; (void)n_in; (void)in_sizes; (void)out_size;

  hipLaunchKernelGGL(cvt_all,     dim3(2048),      dim3(256), 0, stream, x, wq, wk, wv, wo, xb, wb);
  hipLaunchKernelGGL(rope_table,  dim3(256),       dim3(256), 0, stream, tab);
  hipLaunchKernelGGL(gemm_qkv,    dim3(16,64,3),   dim3(256), 0, stream, xb, wb, qkvr);
  hipLaunchKernelGGL(rope_scatter,dim3(32,16,2),   dim3(256), 0, stream, qkvr, Qd, Kd, Vt, tab, pos);
  hipLaunchKernelGGL(attn,        dim3(128,16,2),  dim3(64),  0, stream, Qd, Kd, Vt, Zb);
  hipLaunchKernelGGL(gemm_out,    dim3(16,64),     dim3(256), 0, stream, Zb, wb + 3*NW, out);
}

// Round 2
// 201.175 us; speedup vs baseline: 2.3934x; 2.3934x over previous
//
#include <hip/hip_runtime.h>

// MultiheadSelfAttention: x(2,2048,1024) f32 -> QKV proj + RoPE -> causal attn -> out proj
// Round 2: m97-style LDS GEMMs (global_load_lds w16) + 4-wave LDS-staged flash attn.

#define BATCH 2
#define SEQ   2048
#define NH    16
#define HD    64
#define DM    1024
#define MTOT  (BATCH*SEQ)   // 4096

typedef __attribute__((ext_vector_type(8))) short bf16x8;
typedef __attribute__((ext_vector_type(4))) float f32x4;
typedef unsigned short u16;
typedef unsigned int   u32;

__device__ __forceinline__ float b2f(u16 h){ return __uint_as_float(((u32)h) << 16); }
__device__ __forceinline__ u16 f2b(float f){
  u32 u = __float_as_uint(f);
  u32 r = (u + 0x7FFFu + ((u >> 16) & 1u)) >> 16;   // RNE
  return (u16)r;
}
__device__ __forceinline__ f32x4 mfma16(bf16x8 a, bf16x8 b, f32x4 c){
  return __builtin_amdgcn_mfma_f32_16x16x32_bf16(a, b, c, 0, 0, 0);
}
__device__ __forceinline__ void gload_lds16(const u16* g, u16* l){
  __builtin_amdgcn_global_load_lds((const __attribute__((address_space(1))) unsigned int*)g,
                                   (__attribute__((address_space(3))) unsigned int*)l, 16, 0, 0);
}

// ---------------- fp32 -> bf16 conversion for x and the 4 weights ----------------
__global__ __launch_bounds__(256) void cvt_all(const float* __restrict__ x,
    const float* __restrict__ wq, const float* __restrict__ wk,
    const float* __restrict__ wv, const float* __restrict__ wo,
    u16* __restrict__ xb, u16* __restrict__ wb)
{
  const long NX = (long)MTOT * DM;       // 4194304
  const long NW = (long)DM * DM;         // 1048576
  const long tot4 = (NX + 4*NW) >> 2;
  for (long t = (long)blockIdx.x*blockDim.x + threadIdx.x; t < tot4;
       t += (long)gridDim.x*blockDim.x){
    long e = t << 2;
    const float* s; u16* d;
    if (e < NX){ s = x + e; d = xb + e; }
    else {
      long j = e - NX; int z = (int)(j >> 20);
      const float* ws = (z==0)?wq:(z==1)?wk:(z==2)?wv:wo;
      s = ws + (j & (NW-1)); d = wb + j;
    }
    float4 v = *(const float4*)s;
    u32 lo = (u32)f2b(v.x) | ((u32)f2b(v.y) << 16);
    u32 hi = (u32)f2b(v.z) | ((u32)f2b(v.w) << 16);
    uint2 o; o.x = lo; o.y = hi;
    *(uint2*)d = o;
  }
}

// ---------------- RoPE cos/sin table: [SEQ][32] float2 ----------------
__global__ __launch_bounds__(256) void rope_table(float2* __restrict__ tab){
  int t = blockIdx.x*blockDim.x + threadIdx.x;
  if (t >= SEQ*32) return;
  int s = t >> 5, i = t & 31;
  float inv = 1.0f / powf(10000.0f, (float)i * (1.0f/32.0f));
  float a = (float)s * inv;
  tab[t] = make_float2(cosf(a), sinf(a));
}

// ---------------- m97-style GEMM core: 128x128 tile, BK=32, 4 waves ----------------
// C[m][n] = sum_k A[m][k]*B[n][k]  (both row-major [row][k], lda=ldb=DM)
// Stage via global_load_lds w16: wave w writes LDS chunk (w*2+i)*1024B, lane l -> +16l.
// LDS layout: [128 rows][32 k] linear. row=(w*2+i)*16 + l/4, kcol=(l%4)*8.
__device__ __forceinline__ void gemm128_core(const u16* __restrict__ A, const u16* __restrict__ B,
    int mbase, int nbase, u16* Alds, u16* Blds, f32x4 acc[4][4])
{
  const int tid = threadIdx.x;
  const int w = tid >> 6, l = tid & 63, g = l >> 4, c = l & 15;
  const int wr = (w >> 1)*64, wc = (w & 1)*64;
  const int srow = l >> 2, scol = (l & 3)*8;
  const u16* Ag = A + (long)(mbase + w*32 + srow)*DM + scol;
  const u16* Bg = B + (long)(nbase + w*32 + srow)*DM + scol;
  u16* Alb = Alds + (w*2)*512;   // elems; 1024B chunks
  u16* Blb = Blds + (w*2)*512;

  for (int k0 = 0; k0 < DM; k0 += 32){
    __syncthreads();
    gload_lds16(Ag + k0,           Alb);
    gload_lds16(Ag + 16L*DM + k0,  Alb + 512);
    gload_lds16(Bg + k0,           Blb);
    gload_lds16(Bg + 16L*DM + k0,  Blb + 512);
    __syncthreads();   // compiler drains vmcnt before barrier -> tiles ready
    bf16x8 af[4], bfr[4];
    #pragma unroll
    for (int mi = 0; mi < 4; mi++) af[mi]  = *(const bf16x8*)&Alds[(wr + mi*16 + c)*32 + g*8];
    #pragma unroll
    for (int nj = 0; nj < 4; nj++) bfr[nj] = *(const bf16x8*)&Blds[(wc + nj*16 + c)*32 + g*8];
    #pragma unroll
    for (int mi = 0; mi < 4; mi++)
      #pragma unroll
      for (int nj = 0; nj < 4; nj++)
        acc[mi][nj] = mfma16(af[mi], bfr[nj], acc[mi][nj]);
  }
}

// QKV projection: grid (8, 32, 3), 256 threads. bf16 out to qkvr.
__global__ __launch_bounds__(256) void gemm_qkv(const u16* __restrict__ xb,
                                                const u16* __restrict__ wb,
                                                u16* __restrict__ qkvr)
{
  __shared__ u16 Alds[128*32];
  __shared__ u16 Blds[128*32];
  const int z = blockIdx.z;
  const u16* Bm = wb + (long)z * DM * DM;
  u16* C = qkvr + (long)z * MTOT * DM;
  const int nbase = blockIdx.x*128, mbase = blockIdx.y*128;
  const int w = threadIdx.x >> 6, l = threadIdx.x & 63, g = l >> 4, c = l & 15;
  const int wr = (w >> 1)*64, wc = (w & 1)*64;
  f32x4 acc[4][4] = {};
  gemm128_core(xb, Bm, mbase, nbase, Alds, Blds, acc);
  #pragma unroll
  for (int mi = 0; mi < 4; mi++)
    #pragma unroll
    for (int nj = 0; nj < 4; nj++)
      #pragma unroll
      for (int r = 0; r < 4; r++){
        int row = mbase + wr + mi*16 + 4*g + r;
        int col = nbase + wc + nj*16 + c;
        C[(long)row*DM + col] = f2b(acc[mi][nj][r]);
      }
}

// Output projection: fp32 out to d_out. grid (8, 32)
__global__ __launch_bounds__(256) void gemm_out(const u16* __restrict__ Zb,
                                                const u16* __restrict__ wob,
                                                float* __restrict__ out)
{
  __shared__ u16 Alds[128*32];
  __shared__ u16 Blds[128*32];
  const int nbase = blockIdx.x*128, mbase = blockIdx.y*128;
  const int w = threadIdx.x >> 6, l = threadIdx.x & 63, g = l >> 4, c = l & 15;
  const int wr = (w >> 1)*64, wc = (w & 1)*64;
  f32x4 acc[4][4] = {};
  gemm128_core(Zb, wob, mbase, nbase, Alds, Blds, acc);
  #pragma unroll
  for (int mi = 0; mi < 4; mi++)
    #pragma unroll
    for (int nj = 0; nj < 4; nj++)
      #pragma unroll
      for (int r = 0; r < 4; r++){
        int row = mbase + wr + mi*16 + 4*g + r;
        int col = nbase + wc + nj*16 + c;
        out[(long)row*DM + col] = acc[mi][nj][r];
      }
}

// ---------------- RoPE apply + scatter to attention layouts ----------------
// Q,K: [b,h,s,d] bf16 (rope'd, interleaved pairs).  V: transposed to [b,h,d,s].
__global__ __launch_bounds__(256) void rope_scatter(const u16* __restrict__ qkvr,
    u16* __restrict__ Qd, u16* __restrict__ Kd, u16* __restrict__ Vt,
    const float2* __restrict__ tab, const int* __restrict__ pos)
{
  int st = blockIdx.x, h = blockIdx.y, b = blockIdx.z;
  int s0 = st*64;
  const u16* Qraw = qkvr;
  const u16* Kraw = qkvr + (long)MTOT*DM;
  const u16* Vraw = qkvr + 2L*MTOT*DM;

  for (int t = threadIdx.x; t < 64*32; t += 256){
    int sl = t >> 5, i = t & 31;
    int s = s0 + sl;
    int p = pos[b*SEQ + s];
    if (p < 0) p = 0; if (p >= SEQ) p = SEQ - 1;
    float2 cs = tab[p*32 + i];
    long inoff  = (long)(b*SEQ + s)*DM + h*HD + 2*i;
    long outoff = ((long)(b*NH + h)*SEQ + s)*HD + 2*i;
    u32 qe = *(const u32*)(Qraw + inoff);
    float x1 = b2f((u16)(qe & 0xffff)), x2 = b2f((u16)(qe >> 16));
    float r1 = x1*cs.x - x2*cs.y;
    float r2 = x1*cs.y + x2*cs.x;
    *(u32*)(Qd + outoff) = (u32)f2b(r1) | ((u32)f2b(r2) << 16);
    u32 ke = *(const u32*)(Kraw + inoff);
    x1 = b2f((u16)(ke & 0xffff)); x2 = b2f((u16)(ke >> 16));
    r1 = x1*cs.x - x2*cs.y;
    r2 = x1*cs.y + x2*cs.x;
    *(u32*)(Kd + outoff) = (u32)f2b(r1) | ((u32)f2b(r2) << 16);
  }

  // V transpose 64x64 tile via padded LDS (both global sides coalesced 16B)
  __shared__ u16 vt[64][65];
  for (int t = threadIdx.x; t < 64*8; t += 256){
    int sl = t >> 3, ch = (t & 7)*8;
    bf16x8 v = *(const bf16x8*)(Vraw + (long)(b*SEQ + s0 + sl)*DM + h*HD + ch);
    #pragma unroll
    for (int j = 0; j < 8; j++) vt[sl][ch + j] = (u16)v[j];
  }
  __syncthreads();
  for (int t = threadIdx.x; t < 64*8; t += 256){
    int d = t >> 3, ch = (t & 7)*8;
    bf16x8 v;
    #pragma unroll
    for (int j = 0; j < 8; j++) v[j] = (short)vt[ch + j][d];
    *(bf16x8*)(Vt + ((long)(b*NH + h)*HD + d)*SEQ + s0 + ch) = v;
  }
}

// ---------------- causal flash attention: 4 waves, QBLK=64, KVBLK=64, LDS-staged ----
__global__ __launch_bounds__(256) void attn(const u16* __restrict__ Q, const u16* __restrict__ K,
                                            const u16* __restrict__ Vt, u16* __restrict__ Z)
{
  const int qt = (int)gridDim.x - 1 - (int)blockIdx.x;   // longest first
  const int h = blockIdx.y, b = blockIdx.z;
  const int qbase = qt*64;
  const int tid = threadIdx.x, w = tid >> 6, l = tid & 63, g = l >> 4, c = l & 15;
  const int qrow = qbase + w*16;   // this wave's 16 q-rows
  const u16* Qp = Q  + ((long)(b*NH + h)*SEQ + qrow)*HD;
  const u16* Kp = K  + (long)(b*NH + h)*SEQ*HD;
  const u16* Vp = Vt + (long)(b*NH + h)*HD*SEQ;

  __shared__ u16 K_lds[64][72];   // [key][d], padded
  __shared__ u16 V_lds[64][72];   // [d][key], padded
  __shared__ u16 P_lds[4][16][72];

  bf16x8 qf0 = *(const bf16x8*)(Qp + c*HD + g*8);
  bf16x8 qf1 = *(const bf16x8*)(Qp + c*HD + 32 + g*8);

  f32x4 accz[4] = {};
  float m[4], lsum[4];
  #pragma unroll
  for (int r = 0; r < 4; r++){ m[r] = -1e30f; lsum[r] = 0.f; }

  for (int t = 0; t <= qt; ++t){
    const int kbase = t*64;
    __syncthreads();   // previous tile fully consumed
    #pragma unroll
    for (int i = 0; i < 2; i++){
      int u = tid + i*256;
      int row = u >> 3, ch = (u & 7)*8;
      *(bf16x8*)&K_lds[row][ch] = *(const bf16x8*)(Kp + (long)(kbase + row)*HD + ch);
      *(bf16x8*)&V_lds[row][ch] = *(const bf16x8*)(Vp + (long)row*SEQ + kbase + ch);
    }
    __syncthreads();

    // QK^T: 4 sub-tiles of 16 keys, d accumulated over 2 MFMAs
    f32x4 s[4];
    #pragma unroll
    for (int sub = 0; sub < 4; sub++){
      bf16x8 k0 = *(const bf16x8*)&K_lds[sub*16 + c][g*8];
      bf16x8 k1 = *(const bf16x8*)&K_lds[sub*16 + c][32 + g*8];
      f32x4 z4 = {};
      z4 = mfma16(qf0, k0, z4);
      z4 = mfma16(qf1, k1, z4);
      s[sub] = z4;
    }
    const bool edge = (kbase + 63 > qrow);
    #pragma unroll
    for (int sub = 0; sub < 4; sub++)
      #pragma unroll
      for (int r = 0; r < 4; r++){
        float v = s[sub][r]*0.125f;
        if (edge && (kbase + sub*16 + c > qrow + 4*g + r)) v = -1e30f;
        s[sub][r] = v;
      }

    // online softmax: rows on (g,r); reduce over the 16 c-lanes (shfl stays in-group)
    float tmax[4], f[4], psum[4];
    #pragma unroll
    for (int r = 0; r < 4; r++)
      tmax[r] = fmaxf(fmaxf(s[0][r], s[1][r]), fmaxf(s[2][r], s[3][r]));
    #pragma unroll
    for (int off = 1; off < 16; off <<= 1)
      #pragma unroll
      for (int r = 0; r < 4; r++) tmax[r] = fmaxf(tmax[r], __shfl_xor(tmax[r], off));
    #pragma unroll
    for (int r = 0; r < 4; r++){
      float nm = fmaxf(m[r], tmax[r]);
      f[r] = __expf(m[r] - nm);
      m[r] = nm;
    }
    #pragma unroll
    for (int sub = 0; sub < 4; sub++)
      #pragma unroll
      for (int r = 0; r < 4; r++) s[sub][r] = __expf(s[sub][r] - m[r]);
    #pragma unroll
    for (int r = 0; r < 4; r++) psum[r] = (s[0][r] + s[1][r]) + (s[2][r] + s[3][r]);
    #pragma unroll
    for (int off = 1; off < 16; off <<= 1)
      #pragma unroll
      for (int r = 0; r < 4; r++) psum[r] += __shfl_xor(psum[r], off);
    #pragma unroll
    for (int r = 0; r < 4; r++) lsum[r] = lsum[r]*f[r] + psum[r];
    #pragma unroll
    for (int dt = 0; dt < 4; dt++)
      #pragma unroll
      for (int r = 0; r < 4; r++) accz[dt][r] *= f[r];

    // P (D-layout) -> per-wave LDS -> A-fragment layout for PV (same-wave DS in-order)
    #pragma unroll
    for (int sub = 0; sub < 4; sub++)
      #pragma unroll
      for (int r = 0; r < 4; r++)
        P_lds[w][4*g + r][sub*16 + c] = f2b(s[sub][r]);
    bf16x8 pf0 = *(const bf16x8*)&P_lds[w][c][g*8];
    bf16x8 pf1 = *(const bf16x8*)&P_lds[w][c][32 + g*8];
    #pragma unroll
    for (int dt = 0; dt < 4; dt++){
      bf16x8 vf0 = *(const bf16x8*)&V_lds[dt*16 + c][g*8];
      bf16x8 vf1 = *(const bf16x8*)&V_lds[dt*16 + c][32 + g*8];
      accz[dt] = mfma16(pf0, vf0, accz[dt]);
      accz[dt] = mfma16(pf1, vf1, accz[dt]);
    }
  }

  // epilogue: divide by row-sum, write Z[b, s, h*64+d] bf16
  #pragma unroll
  for (int dt = 0; dt < 4; dt++)
    #pragma unroll
    for (int r = 0; r < 4; r++){
      float zv = accz[dt][r] / lsum[r];
      int row = qrow + 4*g + r;
      int col = dt*16 + c;
      Z[(long)(b*SEQ + row)*DM + h*HD + col] = f2b(zv);
    }
}

extern "C" void kernel_launch(void* const* d_in, const int* in_sizes, int n_in,
                              void* d_out, int out_size, void* d_ws, size_t ws_size,
                              hipStream_t stream)
{
  const float* x  = (const float*)d_in[0];
  const int*   pos= (const int*)d_in[1];
  const float* wq = (const float*)d_in[2];
  const float* wk = (const float*)d_in[3];
  const float* wv = (const float*)d_in[4];
  const float* wo = (const float*)d_in[5];
  float* out = (float*)d_out;

  const long NX = (long)MTOT*DM;
  const long NW = (long)DM*DM;
  char* p = (char*)d_ws;
  u16* xb   = (u16*)p;  p += NX*2;
  u16* wb   = (u16*)p;  p += 4*NW*2;
  u16* qkvr = (u16*)p;  p += 3*NX*2;
  u16* Qd   = (u16*)p;  p += NX*2;
  u16* Kd   = (u16*)p;  p += NX*2;
  u16* Vt   = (u16*)p;  p += NX*2;
  u16* Zb   = (u16*)p;  p += NX*2;
  float2* tab = (float2*)p; p += (long)SEQ*32*sizeof(float2);
  (void)ws_size; (void)n_in; (void)in_sizes; (void)out_size;

  hipLaunchKernelGGL(cvt_all,     dim3(2048),      dim3(256), 0, stream, x, wq, wk, wv, wo, xb, wb);
  hipLaunchKernelGGL(rope_table,  dim3(256),       dim3(256), 0, stream, tab);
  hipLaunchKernelGGL(gemm_qkv,    dim3(8,32,3),    dim3(256), 0, stream, xb, wb, qkvr);
  hipLaunchKernelGGL(rope_scatter,dim3(32,16,2),   dim3(256), 0, stream, qkvr, Qd, Kd, Vt, tab, pos);
  hipLaunchKernelGGL(attn,        dim3(32,16,2),   dim3(256), 0, stream, Qd, Kd, Vt, Zb);
  hipLaunchKernelGGL(gemm_out,    dim3(8,32),      dim3(256), 0, stream, Zb, wb + 3*NW, out);
}

// Round 3
// 164.111 us; speedup vs baseline: 2.9339x; 1.2258x over previous
//
#include <hip/hip_runtime.h>

// MultiheadSelfAttention: x(2,2048,1024) f32 -> QKV proj + RoPE -> causal attn -> out proj
// Round 3: attn rewrite — swapped QK^T (lane-local softmax+P via key-permuted LDS),
//          T2 XOR-swizzled K/V LDS, T14 async double-buffered staging, 1 barrier/tile.

#define BATCH 2
#define SEQ   2048
#define NH    16
#define HD    64
#define DM    1024
#define MTOT  (BATCH*SEQ)   // 4096

typedef __attribute__((ext_vector_type(8))) short bf16x8;
typedef __attribute__((ext_vector_type(4))) float f32x4;
typedef __attribute__((ext_vector_type(4))) unsigned int u32x4;
typedef unsigned short u16;
typedef unsigned int   u32;

__device__ __forceinline__ float b2f(u16 h){ return __uint_as_float(((u32)h) << 16); }
__device__ __forceinline__ u16 f2b(float f){
  u32 u = __float_as_uint(f);
  u32 r = (u + 0x7FFFu + ((u >> 16) & 1u)) >> 16;   // RNE
  return (u16)r;
}
__device__ __forceinline__ u32 pk2(float lo, float hi){
  return (u32)f2b(lo) | ((u32)f2b(hi) << 16);
}
__device__ __forceinline__ f32x4 mfma16(bf16x8 a, bf16x8 b, f32x4 c){
  return __builtin_amdgcn_mfma_f32_16x16x32_bf16(a, b, c, 0, 0, 0);
}
__device__ __forceinline__ void gload_lds16(const u16* g, u16* l){
  __builtin_amdgcn_global_load_lds((const __attribute__((address_space(1))) unsigned int*)g,
                                   (__attribute__((address_space(3))) unsigned int*)l, 16, 0, 0);
}

// ---------------- fp32 -> bf16 conversion for x and the 4 weights ----------------
__global__ __launch_bounds__(256) void cvt_all(const float* __restrict__ x,
    const float* __restrict__ wq, const float* __restrict__ wk,
    const float* __restrict__ wv, const float* __restrict__ wo,
    u16* __restrict__ xb, u16* __restrict__ wb)
{
  const long NX = (long)MTOT * DM;       // 4194304
  const long NW = (long)DM * DM;         // 1048576
  const long tot4 = (NX + 4*NW) >> 2;
  for (long t = (long)blockIdx.x*blockDim.x + threadIdx.x; t < tot4;
       t += (long)gridDim.x*blockDim.x){
    long e = t << 2;
    const float* s; u16* d;
    if (e < NX){ s = x + e; d = xb + e; }
    else {
      long j = e - NX; int z = (int)(j >> 20);
      const float* ws = (z==0)?wq:(z==1)?wk:(z==2)?wv:wo;
      s = ws + (j & (NW-1)); d = wb + j;
    }
    float4 v = *(const float4*)s;
    u32 lo = (u32)f2b(v.x) | ((u32)f2b(v.y) << 16);
    u32 hi = (u32)f2b(v.z) | ((u32)f2b(v.w) << 16);
    uint2 o; o.x = lo; o.y = hi;
    *(uint2*)d = o;
  }
}

// ---------------- RoPE cos/sin table: [SEQ][32] float2 ----------------
__global__ __launch_bounds__(256) void rope_table(float2* __restrict__ tab){
  int t = blockIdx.x*blockDim.x + threadIdx.x;
  if (t >= SEQ*32) return;
  int s = t >> 5, i = t & 31;
  float inv = 1.0f / powf(10000.0f, (float)i * (1.0f/32.0f));
  float a = (float)s * inv;
  tab[t] = make_float2(cosf(a), sinf(a));
}

// ---------------- m97-style GEMM core: 128x128 tile, BK=32, 4 waves ----------------
__device__ __forceinline__ void gemm128_core(const u16* __restrict__ A, const u16* __restrict__ B,
    int mbase, int nbase, u16* Alds, u16* Blds, f32x4 acc[4][4])
{
  const int tid = threadIdx.x;
  const int w = tid >> 6, l = tid & 63, g = l >> 4, c = l & 15;
  const int wr = (w >> 1)*64, wc = (w & 1)*64;
  const int srow = l >> 2, scol = (l & 3)*8;
  const u16* Ag = A + (long)(mbase + w*32 + srow)*DM + scol;
  const u16* Bg = B + (long)(nbase + w*32 + srow)*DM + scol;
  u16* Alb = Alds + (w*2)*512;
  u16* Blb = Blds + (w*2)*512;

  for (int k0 = 0; k0 < DM; k0 += 32){
    __syncthreads();
    gload_lds16(Ag + k0,           Alb);
    gload_lds16(Ag + 16L*DM + k0,  Alb + 512);
    gload_lds16(Bg + k0,           Blb);
    gload_lds16(Bg + 16L*DM + k0,  Blb + 512);
    __syncthreads();
    bf16x8 af[4], bfr[4];
    #pragma unroll
    for (int mi = 0; mi < 4; mi++) af[mi]  = *(const bf16x8*)&Alds[(wr + mi*16 + c)*32 + g*8];
    #pragma unroll
    for (int nj = 0; nj < 4; nj++) bfr[nj] = *(const bf16x8*)&Blds[(wc + nj*16 + c)*32 + g*8];
    #pragma unroll
    for (int mi = 0; mi < 4; mi++)
      #pragma unroll
      for (int nj = 0; nj < 4; nj++)
        acc[mi][nj] = mfma16(af[mi], bfr[nj], acc[mi][nj]);
  }
}

__global__ __launch_bounds__(256) void gemm_qkv(const u16* __restrict__ xb,
                                                const u16* __restrict__ wb,
                                                u16* __restrict__ qkvr)
{
  __shared__ u16 Alds[128*32];
  __shared__ u16 Blds[128*32];
  const int z = blockIdx.z;
  const u16* Bm = wb + (long)z * DM * DM;
  u16* C = qkvr + (long)z * MTOT * DM;
  const int nbase = blockIdx.x*128, mbase = blockIdx.y*128;
  const int w = threadIdx.x >> 6, l = threadIdx.x & 63, g = l >> 4, c = l & 15;
  const int wr = (w >> 1)*64, wc = (w & 1)*64;
  f32x4 acc[4][4] = {};
  gemm128_core(xb, Bm, mbase, nbase, Alds, Blds, acc);
  #pragma unroll
  for (int mi = 0; mi < 4; mi++)
    #pragma unroll
    for (int nj = 0; nj < 4; nj++)
      #pragma unroll
      for (int r = 0; r < 4; r++){
        int row = mbase + wr + mi*16 + 4*g + r;
        int col = nbase + wc + nj*16 + c;
        C[(long)row*DM + col] = f2b(acc[mi][nj][r]);
      }
}

__global__ __launch_bounds__(256) void gemm_out(const u16* __restrict__ Zb,
                                                const u16* __restrict__ wob,
                                                float* __restrict__ out)
{
  __shared__ u16 Alds[128*32];
  __shared__ u16 Blds[128*32];
  const int nbase = blockIdx.x*128, mbase = blockIdx.y*128;
  const int w = threadIdx.x >> 6, l = threadIdx.x & 63, g = l >> 4, c = l & 15;
  const int wr = (w >> 1)*64, wc = (w & 1)*64;
  f32x4 acc[4][4] = {};
  gemm128_core(Zb, wob, mbase, nbase, Alds, Blds, acc);
  #pragma unroll
  for (int mi = 0; mi < 4; mi++)
    #pragma unroll
    for (int nj = 0; nj < 4; nj++)
      #pragma unroll
      for (int r = 0; r < 4; r++){
        int row = mbase + wr + mi*16 + 4*g + r;
        int col = nbase + wc + nj*16 + c;
        out[(long)row*DM + col] = acc[mi][nj][r];
      }
}

// ---------------- RoPE apply + scatter to attention layouts ----------------
__global__ __launch_bounds__(256) void rope_scatter(const u16* __restrict__ qkvr,
    u16* __restrict__ Qd, u16* __restrict__ Kd, u16* __restrict__ Vt,
    const float2* __restrict__ tab, const int* __restrict__ pos)
{
  int st = blockIdx.x, h = blockIdx.y, b = blockIdx.z;
  int s0 = st*64;
  const u16* Qraw = qkvr;
  const u16* Kraw = qkvr + (long)MTOT*DM;
  const u16* Vraw = qkvr + 2L*MTOT*DM;

  for (int t = threadIdx.x; t < 64*32; t += 256){
    int sl = t >> 5, i = t & 31;
    int s = s0 + sl;
    int p = pos[b*SEQ + s];
    if (p < 0) p = 0; if (p >= SEQ) p = SEQ - 1;
    float2 cs = tab[p*32 + i];
    long inoff  = (long)(b*SEQ + s)*DM + h*HD + 2*i;
    long outoff = ((long)(b*NH + h)*SEQ + s)*HD + 2*i;
    u32 qe = *(const u32*)(Qraw + inoff);
    float x1 = b2f((u16)(qe & 0xffff)), x2 = b2f((u16)(qe >> 16));
    float r1 = x1*cs.x - x2*cs.y;
    float r2 = x1*cs.y + x2*cs.x;
    *(u32*)(Qd + outoff) = (u32)f2b(r1) | ((u32)f2b(r2) << 16);
    u32 ke = *(const u32*)(Kraw + inoff);
    x1 = b2f((u16)(ke & 0xffff)); x2 = b2f((u16)(ke >> 16));
    r1 = x1*cs.x - x2*cs.y;
    r2 = x1*cs.y + x2*cs.x;
    *(u32*)(Kd + outoff) = (u32)f2b(r1) | ((u32)f2b(r2) << 16);
  }

  __shared__ u16 vt[64][65];
  for (int t = threadIdx.x; t < 64*8; t += 256){
    int sl = t >> 3, ch = (t & 7)*8;
    bf16x8 v = *(const bf16x8*)(Vraw + (long)(b*SEQ + s0 + sl)*DM + h*HD + ch);
    #pragma unroll
    for (int j = 0; j < 8; j++) vt[sl][ch + j] = (u16)v[j];
  }
  __syncthreads();
  for (int t = threadIdx.x; t < 64*8; t += 256){
    int d = t >> 3, ch = (t & 7)*8;
    bf16x8 v;
    #pragma unroll
    for (int j = 0; j < 8; j++) v[j] = (short)vt[ch + j][d];
    *(bf16x8*)(Vt + ((long)(b*NH + h)*HD + d)*SEQ + s0 + ch) = v;
  }
}

// ---------------- causal flash attention -----------------------------------
// 4 waves, QBLK=64 (16 q/wave), KVBLK=64. Swapped QK^T: S^T = mfma(K,Q) so each
// lane owns query q=c with 16 key-scores in regs. K rows permuted in LDS so the
// owned keys are exactly the PV A-frag chunks (P stays in registers, 0 shuffles).
// stored_row(a) = (a&32)|((a&4)<<2)|((a&24)>>1)|(a&3); lane (g,c) sub s, reg r
//   <-> actual key (s>>1)*32 + 8g + 4*(s&1) + r.
// K/V LDS: [2 bufs][64][64] bf16, XOR-swizzled (chunk ^= row&7) both sides.
__device__ __forceinline__ int kperm(int a){
  return (a & 32) | ((a & 4) << 2) | ((a & 24) >> 1) | (a & 3);
}

__global__ __launch_bounds__(256) void attn(const u16* __restrict__ Q, const u16* __restrict__ K,
                                            const u16* __restrict__ Vt, u16* __restrict__ Z)
{
  const int qt = (int)gridDim.x - 1 - (int)blockIdx.x;   // longest first
  const int h = blockIdx.y, b = blockIdx.z;
  const int qbase = qt*64;
  const int tid = threadIdx.x, w = tid >> 6, l = tid & 63, g = l >> 4, c = l & 15;
  const int qrow = qbase + w*16;   // this wave's 16 q-rows
  const u16* Qp = Q  + ((long)(b*NH + h)*SEQ + qrow)*HD;
  const u16* Kp = K  + (long)(b*NH + h)*SEQ*HD;
  const u16* Vp = Vt + (long)(b*NH + h)*HD*SEQ;

  __shared__ u16 K_lds[2][64][64];
  __shared__ u16 V_lds[2][64][64];

  // Q B-fragments: col=c -> query qrow+c, d-chunks g*8 and 32+g*8
  bf16x8 qf0 = *(const bf16x8*)(Qp + c*HD + g*8);
  bf16x8 qf1 = *(const bf16x8*)(Qp + c*HD + 32 + g*8);

  // staging: thread covers (row = u>>3, chunk = u&7) for u = tid, tid+256
  const int srow0 = tid >> 3, sch = tid & 7;
  const int kpr0 = kperm(srow0), kpr1 = kperm(srow0 + 32);

  f32x4 accz[4] = {};
  float m = -1e30f, lsum = 0.f;
  const int cswz = c & 7;

  bf16x8 kr[2], vr[2];
  // prologue: tile 0 -> regs -> LDS buf 0
  #pragma unroll
  for (int i = 0; i < 2; i++){
    int row = srow0 + i*32;
    kr[i] = *(const bf16x8*)(Kp + (long)row*HD + sch*8);
    vr[i] = *(const bf16x8*)(Vp + (long)row*SEQ + sch*8);
  }
  {
    *(bf16x8*)&K_lds[0][kpr0][(sch ^ (kpr0 & 7))*8] = kr[0];
    *(bf16x8*)&K_lds[0][kpr1][(sch ^ (kpr1 & 7))*8] = kr[1];
    *(bf16x8*)&V_lds[0][srow0][(sch ^ (srow0 & 7))*8] = vr[0];
    *(bf16x8*)&V_lds[0][srow0+32][(sch ^ ((srow0+32) & 7))*8] = vr[1];
  }

  int cur = 0;
  for (int t = 0; t <= qt; ++t){
    const int kbase = t*64;
    __syncthreads();   // buf `cur` ready; all prior reads of cur^1 done

    if (t < qt){       // T14: issue next tile's global loads now, write LDS later
      const int nb = kbase + 64;
      #pragma unroll
      for (int i = 0; i < 2; i++){
        int row = srow0 + i*32;
        kr[i] = *(const bf16x8*)(Kp + (long)(nb + row)*HD + sch*8);
        vr[i] = *(const bf16x8*)(Vp + (long)row*SEQ + nb + sch*8);
      }
    }

    // QK^T (swapped): s[sub][r] = S_stored[sub*16+4g+r][q=c]
    f32x4 s[4];
    #pragma unroll
    for (int sub = 0; sub < 4; sub++){
      int row = sub*16 + c;
      bf16x8 ka0 = *(const bf16x8*)&K_lds[cur][row][((0+g) ^ cswz)*8];
      bf16x8 ka1 = *(const bf16x8*)&K_lds[cur][row][((4+g) ^ cswz)*8];
      f32x4 z4 = {};
      z4 = mfma16(ka0, qf0, z4);
      z4 = mfma16(ka1, qf1, z4);
      s[sub] = z4;
    }

    // scale + causal mask (actual key from permutation map)
    const bool edge = (kbase + 63 > qrow);
    const int q = qrow + c;
    #pragma unroll
    for (int sub = 0; sub < 4; sub++)
      #pragma unroll
      for (int r = 0; r < 4; r++){
        float v = s[sub][r]*0.125f;
        if (edge){
          int key = kbase + ((sub >> 1) << 5) + 8*g + ((sub & 1) << 2) + r;
          if (key > q) v = -1e30f;
        }
        s[sub][r] = v;
      }

    // online softmax: 16 in-lane values for query q=c; reduce across g via 2 shfl
    float tmax = s[0][0];
    #pragma unroll
    for (int sub = 0; sub < 4; sub++)
      #pragma unroll
      for (int r = 0; r < 4; r++) tmax = fmaxf(tmax, s[sub][r]);
    tmax = fmaxf(tmax, __shfl_xor(tmax, 16));
    tmax = fmaxf(tmax, __shfl_xor(tmax, 32));
    float nm = fmaxf(m, tmax);
    float f = __expf(m - nm);
    m = nm;
    float psum = 0.f;
    #pragma unroll
    for (int sub = 0; sub < 4; sub++)
      #pragma unroll
      for (int r = 0; r < 4; r++){
        float e = __expf(s[sub][r] - m);
        s[sub][r] = e;
        psum += e;
      }
    psum += __shfl_xor(psum, 16);
    psum += __shfl_xor(psum, 32);
    lsum = lsum*f + psum;

    // broadcast rescale factors to output-row owners (q = 4g+r rows)
    float f_bc[4];
    #pragma unroll
    for (int r = 0; r < 4; r++) f_bc[r] = __shfl(f, 4*g + r);
    #pragma unroll
    for (int dt = 0; dt < 4; dt++)
      #pragma unroll
      for (int r = 0; r < 4; r++) accz[dt][r] *= f_bc[r];

    // P -> bf16 A-frags, fully in-lane (keys 8g..8g+7 and 32+8g..+7)
    u32x4 p0, p1;
    p0[0] = pk2(s[0][0], s[0][1]); p0[1] = pk2(s[0][2], s[0][3]);
    p0[2] = pk2(s[1][0], s[1][1]); p0[3] = pk2(s[1][2], s[1][3]);
    p1[0] = pk2(s[2][0], s[2][1]); p1[1] = pk2(s[2][2], s[2][3]);
    p1[2] = pk2(s[3][0], s[3][1]); p1[3] = pk2(s[3][2], s[3][3]);
    bf16x8 pf0 = __builtin_bit_cast(bf16x8, p0);
    bf16x8 pf1 = __builtin_bit_cast(bf16x8, p1);

    // PV: Z[q=4g+r][d=dt*16+c] += P[q][k] V[k][d]
    #pragma unroll
    for (int dt = 0; dt < 4; dt++){
      int vrow = dt*16 + c;
      bf16x8 vf0 = *(const bf16x8*)&V_lds[cur][vrow][((0+g) ^ cswz)*8];
      bf16x8 vf1 = *(const bf16x8*)&V_lds[cur][vrow][((4+g) ^ cswz)*8];
      accz[dt] = mfma16(pf0, vf0, accz[dt]);
      accz[dt] = mfma16(pf1, vf1, accz[dt]);
    }

    if (t < qt){   // write next tile into the other buffer (no barrier needed)
      int nx = cur ^ 1;
      *(bf16x8*)&K_lds[nx][kpr0][(sch ^ (kpr0 & 7))*8] = kr[0];
      *(bf16x8*)&K_lds[nx][kpr1][(sch ^ (kpr1 & 7))*8] = kr[1];
      *(bf16x8*)&V_lds[nx][srow0][(sch ^ (srow0 & 7))*8] = vr[0];
      *(bf16x8*)&V_lds[nx][srow0+32][(sch ^ ((srow0+32) & 7))*8] = vr[1];
      cur = nx;
    }
  }

  // epilogue: lsum lives at lane (0, q); broadcast to output-row owners
  float lsum_bc[4];
  #pragma unroll
  for (int r = 0; r < 4; r++) lsum_bc[r] = __shfl(lsum, 4*g + r);
  #pragma unroll
  for (int dt = 0; dt < 4; dt++)
    #pragma unroll
    for (int r = 0; r < 4; r++){
      float zv = accz[dt][r] / lsum_bc[r];
      int row = qrow + 4*g + r;
      int col = dt*16 + c;
      Z[(long)(b*SEQ + row)*DM + h*HD + col] = f2b(zv);
    }
}

extern "C" void kernel_launch(void* const* d_in, const int* in_sizes, int n_in,
                              void* d_out, int out_size, void* d_ws, size_t ws_size,
                              hipStream_t stream)
{
  const float* x  = (const float*)d_in[0];
  const int*   pos= (const int*)d_in[1];
  const float* wq = (const float*)d_in[2];
  const float* wk = (const float*)d_in[3];
  const float* wv = (const float*)d_in[4];
  const float* wo = (const float*)d_in[5];
  float* out = (float*)d_out;

  const long NX = (long)MTOT*DM;
  const long NW = (long)DM*DM;
  char* p = (char*)d_ws;
  u16* xb   = (u16*)p;  p += NX*2;
  u16* wb   = (u16*)p;  p += 4*NW*2;
  u16* qkvr = (u16*)p;  p += 3*NX*2;
  u16* Qd   = (u16*)p;  p += NX*2;
  u16* Kd   = (u16*)p;  p += NX*2;
  u16* Vt   = (u16*)p;  p += NX*2;
  u16* Zb   = (u16*)p;  p += NX*2;
  float2* tab = (float2*)p; p += (long)SEQ*32*sizeof(float2);
  (void)ws_size; (void)n_in; (void)in_sizes; (void)out_size;

  hipLaunchKernelGGL(cvt_all,     dim3(2048),      dim3(256), 0, stream, x, wq, wk, wv, wo, xb, wb);
  hipLaunchKernelGGL(rope_table,  dim3(256),       dim3(256), 0, stream, tab);
  hipLaunchKernelGGL(gemm_qkv,    dim3(8,32,3),    dim3(256), 0, stream, xb, wb, qkvr);
  hipLaunchKernelGGL(rope_scatter,dim3(32,16,2),   dim3(256), 0, stream, qkvr, Qd, Kd, Vt, tab, pos);
  hipLaunchKernelGGL(attn,        dim3(32,16,2),   dim3(256), 0, stream, Qd, Kd, Vt, Zb);
  hipLaunchKernelGGL(gemm_out,    dim3(8,32),      dim3(256), 0, stream, Zb, wb + 3*NW, out);
}